// Round 1
// baseline (643.490 us; speedup 1.0000x reference)
//
#include <hip/hip_runtime.h>

#define N_NODES 100000
#define N_EDGES 1600000
#define IN_DIM 512
#define HID_DIM 128
#define OUT_DIM 64

typedef __attribute__((ext_vector_type(8))) short bf16x8;
typedef __attribute__((ext_vector_type(4))) float f32x4;

__device__ __forceinline__ unsigned int f2bf_rne(float f) {
    union { float f; unsigned u; } v; v.f = f;
    unsigned r = v.u + 0x7fffu + ((v.u >> 16) & 1u);   // round-to-nearest-even
    return r >> 16;
}

// ---------------------------------------------------------------------------
// wcvt: W1t[128][512] bf16 = transpose(W1[512][128] fp32)   (one-shot, 16 blk)
// ---------------------------------------------------------------------------
__global__ __launch_bounds__(256) void wcvt(const float* __restrict__ W1,
                                            unsigned short* __restrict__ W1t) {
    __shared__ float T[64][65];
    const int bk = blockIdx.x >> 1;
    const int bn = blockIdx.x & 1;
    const int t = threadIdx.x;
#pragma unroll
    for (int i = 0; i < 4; i++) {
        int fi = t + i * 256;
        int kk = fi >> 4;
        int f  = fi & 15;
        float4 v = *(const float4*)&W1[(long)(bk * 64 + kk) * HID_DIM + bn * 64 + f * 4];
        T[kk][f * 4 + 0] = v.x; T[kk][f * 4 + 1] = v.y;
        T[kk][f * 4 + 2] = v.z; T[kk][f * 4 + 3] = v.w;
    }
    __syncthreads();
#pragma unroll
    for (int i = 0; i < 8; i++) {
        int di = t + i * 256;
        int n  = di >> 5;
        int dw = di & 31;
        unsigned lo = f2bf_rne(T[dw * 2 + 0][n]);
        unsigned hi = f2bf_rne(T[dw * 2 + 1][n]);
        unsigned short* dst = W1t + (long)(bn * 64 + n) * IN_DIM + bk * 64 + dw * 2;
        *(unsigned int*)dst = lo | (hi << 16);
    }
}

// ---------------------------------------------------------------------------
// wcvt2: W2t[64][128] bf16 = transpose(W2[128][64] fp32)   (one-shot, 1 blk)
// ---------------------------------------------------------------------------
__global__ __launch_bounds__(256) void wcvt2(const float* __restrict__ W2,
                                             unsigned short* __restrict__ W2t) {
    __shared__ float T[128][65];
    const int t = threadIdx.x;
#pragma unroll
    for (int i = 0; i < 8; i++) {
        int fi = t + i * 256;
        int k = fi >> 4;
        int f = fi & 15;
        float4 v = *(const float4*)&W2[(long)k * OUT_DIM + f * 4];
        T[k][f * 4 + 0] = v.x; T[k][f * 4 + 1] = v.y;
        T[k][f * 4 + 2] = v.z; T[k][f * 4 + 3] = v.w;
    }
    __syncthreads();
#pragma unroll
    for (int i = 0; i < 16; i++) {
        int di = t + i * 256;
        int n  = di >> 6;
        int dw = di & 63;
        unsigned lo = f2bf_rne(T[dw * 2 + 0][n]);
        unsigned hi = f2bf_rne(T[dw * 2 + 1][n]);
        *(unsigned int*)(W2t + (long)n * HID_DIM + dw * 2) = lo | (hi << 16);
    }
}

// ---------------------------------------------------------------------------
// gemm1_mfma: support_bf16[100000,128] = X[100000,512] @ W1  (bf16 MFMA)
// ---------------------------------------------------------------------------
__global__ __launch_bounds__(256) void gemm1_mfma(const float* __restrict__ X,
                                                  const unsigned short* __restrict__ W1t,
                                                  unsigned short* __restrict__ outb) {
    __shared__ unsigned short As[64][40];
    const int tid  = threadIdx.x;
    const int lane = tid & 63;
    const int w    = tid >> 6;
    const int m    = lane & 15;
    const int hi   = lane >> 4;
    const int rowBase = blockIdx.x * 64;

    f32x4 acc[4][2] = {};

    const int sr = tid >> 2;
    const int sk = (tid & 3) * 8;
    int gr = rowBase + sr;
    if (gr >= N_NODES) gr = N_NODES - 1;
    const float* xp = X + (long)gr * IN_DIM;

    const unsigned short* b0p = W1t + (long)(w * 32 + m) * IN_DIM + hi * 8;
    const unsigned short* b1p = W1t + (long)(w * 32 + 16 + m) * IN_DIM + hi * 8;

    for (int k0 = 0; k0 < IN_DIM; k0 += 32) {
        float4 xa = *(const float4*)(xp + k0 + sk);
        float4 xb = *(const float4*)(xp + k0 + sk + 4);
        uint4 pk;
        pk.x = f2bf_rne(xa.x) | (f2bf_rne(xa.y) << 16);
        pk.y = f2bf_rne(xa.z) | (f2bf_rne(xa.w) << 16);
        pk.z = f2bf_rne(xb.x) | (f2bf_rne(xb.y) << 16);
        pk.w = f2bf_rne(xb.z) | (f2bf_rne(xb.w) << 16);
        *(uint4*)&As[sr][sk] = pk;
        __syncthreads();

        bf16x8 bf0 = *(const bf16x8*)(b0p + k0);
        bf16x8 bf1 = *(const bf16x8*)(b1p + k0);
#pragma unroll
        for (int t = 0; t < 4; t++) {
            bf16x8 af = *(const bf16x8*)&As[t * 16 + m][hi * 8];
            acc[t][0] = __builtin_amdgcn_mfma_f32_16x16x32_bf16(af, bf0, acc[t][0], 0, 0, 0);
            acc[t][1] = __builtin_amdgcn_mfma_f32_16x16x32_bf16(af, bf1, acc[t][1], 0, 0, 0);
        }
        __syncthreads();
    }

    // D layout: col = lane&15, row = (lane>>4)*4 + reg ; store bf16
#pragma unroll
    for (int t = 0; t < 4; t++) {
#pragma unroll
        for (int r = 0; r < 4; r++) {
            int row = rowBase + t * 16 + hi * 4 + r;
            if (row < N_NODES) {
                outb[(long)row * HID_DIM + w * 32 + m] =
                    (unsigned short)f2bf_rne(acc[t][0][r]);
                outb[(long)row * HID_DIM + w * 32 + 16 + m] =
                    (unsigned short)f2bf_rne(acc[t][1][r]);
            }
        }
    }
}

// ---------------------------------------------------------------------------
// gemm2_mfma: hw[100000,64] fp32 = h_bf16[100000,128] @ W2  (W2 in registers)
// ---------------------------------------------------------------------------
__global__ __launch_bounds__(256) void gemm2_mfma(const unsigned short* __restrict__ hb,
                                                  const unsigned short* __restrict__ W2t,
                                                  float* __restrict__ hw) {
    const int tid  = threadIdx.x;
    const int lane = tid & 63;
    const int w    = tid >> 6;
    const int m    = lane & 15;
    const int hi   = lane >> 4;
    const long rowBase = (long)blockIdx.x * 128 + w * 32;

    bf16x8 bfrag[4][4];
#pragma unroll
    for (int nt = 0; nt < 4; nt++) {
        const unsigned short* bp = W2t + (long)(nt * 16 + m) * HID_DIM + hi * 8;
#pragma unroll
        for (int ks = 0; ks < 4; ks++)
            bfrag[ks][nt] = *(const bf16x8*)(bp + ks * 32);
    }

    f32x4 acc[2][4] = {};
#pragma unroll
    for (int mt = 0; mt < 2; mt++) {
        long r = rowBase + mt * 16 + m;
        if (r >= N_NODES) r = N_NODES - 1;
        const unsigned short* ap = hb + r * HID_DIM + hi * 8;
#pragma unroll
        for (int ks = 0; ks < 4; ks++) {
            bf16x8 af = *(const bf16x8*)(ap + ks * 32);
#pragma unroll
            for (int nt = 0; nt < 4; nt++)
                acc[mt][nt] = __builtin_amdgcn_mfma_f32_16x16x32_bf16(
                    af, bfrag[ks][nt], acc[mt][nt], 0, 0, 0);
        }
    }

#pragma unroll
    for (int mt = 0; mt < 2; mt++)
#pragma unroll
        for (int nt = 0; nt < 4; nt++)
#pragma unroll
            for (int r = 0; r < 4; r++) {
                long row = rowBase + mt * 16 + hi * 4 + r;
                if (row < N_NODES)
                    hw[row * OUT_DIM + nt * 16 + m] = acc[mt][nt][r];
            }
}

// ---------------------------------------------------------------------------
// CSR build: histogram -> 3-phase parallel exclusive scan -> scatter (packed)
// ---------------------------------------------------------------------------
__global__ __launch_bounds__(256) void hist_rows(const int* __restrict__ rows,
                                                 int* __restrict__ cnt) {
    int e = blockIdx.x * 256 + threadIdx.x;
    if (e < N_EDGES) atomicAdd(&cnt[rows[e]], 1);
}

#define SCAN_BLOCKS ((N_NODES + 255) / 256)   // 391

__global__ __launch_bounds__(256) void scan_pass1(int* __restrict__ cnt,
                                                  int* __restrict__ bsum) {
    __shared__ int s[256];
    const int t = threadIdx.x;
    const int i = blockIdx.x * 256 + t;
    int v = (i < N_NODES) ? cnt[i] : 0;
    s[t] = v;
    __syncthreads();
    for (int off = 1; off < 256; off <<= 1) {
        int u = (t >= off) ? s[t - off] : 0;
        __syncthreads();
        s[t] += u;
        __syncthreads();
    }
    if (i < N_NODES) cnt[i] = s[t] - v;
    if (t == 255) bsum[blockIdx.x] = s[255];
}

__global__ __launch_bounds__(512) void scan_pass2(int* __restrict__ bsum,
                                                  int* __restrict__ boff) {
    __shared__ int s[512];
    const int t = threadIdx.x;
    int v = (t < SCAN_BLOCKS) ? bsum[t] : 0;
    s[t] = v;
    __syncthreads();
    for (int off = 1; off < 512; off <<= 1) {
        int u = (t >= off) ? s[t - off] : 0;
        __syncthreads();
        s[t] += u;
        __syncthreads();
    }
    if (t < SCAN_BLOCKS) boff[t] = s[t] - v;
}

__global__ __launch_bounds__(256) void scan_pass3(const int* __restrict__ cnt,
                                                  const int* __restrict__ boff,
                                                  int* __restrict__ rowptr,
                                                  int* __restrict__ cursor) {
    const int i = blockIdx.x * 256 + threadIdx.x;
    if (i < N_NODES) {
        int r = cnt[i] + boff[blockIdx.x];
        rowptr[i] = r;
        cursor[i] = r;
    }
    if (i == 0) rowptr[N_NODES] = N_EDGES;
}

__global__ __launch_bounds__(256) void scatter_edges(const int* __restrict__ rows,
                                                     const int* __restrict__ cols,
                                                     const float* __restrict__ vals,
                                                     int* __restrict__ cursor,
                                                     int2* __restrict__ sedge) {
    int e = blockIdx.x * 256 + threadIdx.x;
    if (e < N_EDGES) {
        int p = atomicAdd(&cursor[rows[e]], 1);
        sedge[p] = make_int2(cols[e], __float_as_int(vals[e]));
    }
}

// ---------------------------------------------------------------------------
// spmm1: h_bf16[row] = relu(sum v * support_bf16[col]) ; wave/row, D=128
//
// Latency restructure: each wave loads up to 64 edges of its row in ONE
// coalesced dwordx2/lane, then broadcasts (col,val) via readlane (loop index
// is wave-uniform -> SALU broadcast, gather base lands in SGPRs). Gathers
// issue 8-at-a-time with no intervening waits (MLP 2 -> 8). Padding lanes
// hold {0,0}: pad gathers hit row 0 (L1-hot) and multiply by 0.
// ---------------------------------------------------------------------------
__global__ __launch_bounds__(256) void spmm1(const int* __restrict__ rowptr,
                                             const int2* __restrict__ sedge,
                                             const unsigned short* __restrict__ supb,
                                             unsigned short* __restrict__ outb) {
    const int wid = blockIdx.x * 4 + (threadIdx.x >> 6);
    if (wid >= N_NODES) return;
    const int lane = threadIdx.x & 63;
    const int start = rowptr[wid];
    const int end   = rowptr[wid + 1];

    float accx = 0.f, accy = 0.f;

    for (int base = start; base < end; base += 64) {
        int idx = base + lane;
        int ecol = 0, eval = 0;
        if (idx < end) {
            int2 e = sedge[idx];
            ecol = e.x; eval = e.y;
        }
        const int cnt = min(64, end - base);
        for (int k = 0; k < cnt; k += 8) {
            int   c[8];
            float v[8];
#pragma unroll
            for (int q = 0; q < 8; q++) {
                c[q] = __builtin_amdgcn_readlane(ecol, k + q);
                v[q] = __int_as_float(__builtin_amdgcn_readlane(eval, k + q));
            }
            unsigned u[8];
#pragma unroll
            for (int q = 0; q < 8; q++)
                u[q] = *(const unsigned*)(supb + (long)c[q] * 128 + lane * 2);
#pragma unroll
            for (int q = 0; q < 8; q++) {
                accx += v[q] * __uint_as_float(u[q] << 16);
                accy += v[q] * __uint_as_float(u[q] & 0xffff0000u);
            }
        }
    }

    accx = accx > 0.f ? accx : 0.f;
    accy = accy > 0.f ? accy : 0.f;
    *(unsigned int*)(outb + (long)wid * 128 + lane * 2) =
        f2bf_rne(accx) | (f2bf_rne(accy) << 16);
}

// ---------------------------------------------------------------------------
// spmm2: out[row] = sum v * hw[col] ; wave/row, D=64, fp32 (logits path)
// Same lane-parallel edge fetch + readlane broadcast as spmm1.
// ---------------------------------------------------------------------------
__global__ __launch_bounds__(256) void spmm2(const int* __restrict__ rowptr,
                                             const int2* __restrict__ sedge,
                                             const float* __restrict__ dense,
                                             float* __restrict__ out) {
    const int wid = blockIdx.x * 4 + (threadIdx.x >> 6);
    if (wid >= N_NODES) return;
    const int lane = threadIdx.x & 63;
    const int start = rowptr[wid];
    const int end   = rowptr[wid + 1];

    float acc = 0.f;

    for (int base = start; base < end; base += 64) {
        int idx = base + lane;
        int ecol = 0, eval = 0;
        if (idx < end) {
            int2 e = sedge[idx];
            ecol = e.x; eval = e.y;
        }
        const int cnt = min(64, end - base);
        for (int k = 0; k < cnt; k += 8) {
            int   c[8];
            float v[8];
#pragma unroll
            for (int q = 0; q < 8; q++) {
                c[q] = __builtin_amdgcn_readlane(ecol, k + q);
                v[q] = __int_as_float(__builtin_amdgcn_readlane(eval, k + q));
            }
            float x[8];
#pragma unroll
            for (int q = 0; q < 8; q++)
                x[q] = dense[(long)c[q] * 64 + lane];
#pragma unroll
            for (int q = 0; q < 8; q++)
                acc += v[q] * x[q];
        }
    }

    out[(long)wid * 64 + lane] = acc;
}

// ---------------------------------------------------------------------------
extern "C" void kernel_launch(void* const* d_in, const int* in_sizes, int n_in,
                              void* d_out, int out_size, void* d_ws, size_t ws_size,
                              hipStream_t stream) {
    const float* feature = (const float*)d_in[0];
    const int*   erow    = (const int*)d_in[1];
    const int*   ecol    = (const int*)d_in[2];
    const float* evals   = (const float*)d_in[3];
    const float* W1      = (const float*)d_in[4];
    const float* W2      = (const float*)d_in[5];
    float* out = (float*)d_out;

    // workspace layout (~91 MB)
    unsigned short* supb = (unsigned short*)d_ws;                 // 25.6 MB bf16
    unsigned short* hb   = supb + (size_t)N_NODES * HID_DIM;      // 25.6 MB bf16
    float* hw      = (float*)(hb + (size_t)N_NODES * HID_DIM);    // 25.6 MB fp32
    int*   cnt     = (int*)(hw + (size_t)N_NODES * OUT_DIM);      // 400 KB
    int*   cursor  = cnt + N_NODES;                               // 400 KB
    int*   rowptr  = cursor + N_NODES;                            // 400 KB
    int2*  sedge   = (int2*)(rowptr + (N_NODES + 1));             // 12.8 MB
    int*   bsum    = (int*)(sedge + N_EDGES);                     // 1.6 KB
    int*   boff    = bsum + SCAN_BLOCKS;                          // 1.6 KB
    unsigned short* W1t = (unsigned short*)(boff + SCAN_BLOCKS);  // 128 KB bf16
    unsigned short* W2t = W1t + (size_t)HID_DIM * IN_DIM;         // 16 KB bf16

    // --- CSR build (counting sort by row) ---
    hipMemsetAsync(cnt, 0, (size_t)N_NODES * sizeof(int), stream);
    hist_rows<<<(N_EDGES + 255) / 256, 256, 0, stream>>>(erow, cnt);
    scan_pass1<<<SCAN_BLOCKS, 256, 0, stream>>>(cnt, bsum);
    scan_pass2<<<1, 512, 0, stream>>>(bsum, boff);
    scan_pass3<<<SCAN_BLOCKS, 256, 0, stream>>>(cnt, boff, rowptr, cursor);
    scatter_edges<<<(N_EDGES + 255) / 256, 256, 0, stream>>>(erow, ecol, evals,
                                                             cursor, sedge);

    // --- weight conversions (one-shot, tiny) ---
    wcvt<<<16, 256, 0, stream>>>(W1, W1t);
    wcvt2<<<1, 256, 0, stream>>>(W2, W2t);

    // layer 1: support = X @ W1  -> bf16
    gemm1_mfma<<<(N_NODES + 63) / 64, 256, 0, stream>>>(feature, W1t, supb);

    // h = relu(A @ support) -> bf16
    spmm1<<<(N_NODES + 3) / 4, 256, 0, stream>>>(rowptr, sedge, supb, hb);

    // hw = h @ W2 -> fp32
    gemm2_mfma<<<(N_NODES + 127) / 128, 256, 0, stream>>>(hb, W2t, hw);

    // logits = A @ hw
    spmm2<<<(N_NODES + 3) / 4, 256, 0, stream>>>(rowptr, sedge, hw, out);
}

// Round 3
// 606.251 us; speedup vs baseline: 1.0614x; 1.0614x over previous
//
#include <hip/hip_runtime.h>

#define N_NODES 100000
#define N_EDGES 1600000
#define IN_DIM 512
#define HID_DIM 128
#define OUT_DIM 64

typedef __attribute__((ext_vector_type(8))) short bf16x8;
typedef __attribute__((ext_vector_type(4))) float f32x4;

__device__ __forceinline__ unsigned int f2bf_rne(float f) {
    union { float f; unsigned u; } v; v.f = f;
    unsigned r = v.u + 0x7fffu + ((v.u >> 16) & 1u);   // round-to-nearest-even
    return r >> 16;
}

// ---------------------------------------------------------------------------
// wcvt: W1t[128][512] bf16 = transpose(W1[512][128] fp32)   (one-shot, 16 blk)
// ---------------------------------------------------------------------------
__global__ __launch_bounds__(256) void wcvt(const float* __restrict__ W1,
                                            unsigned short* __restrict__ W1t) {
    __shared__ float T[64][65];
    const int bk = blockIdx.x >> 1;
    const int bn = blockIdx.x & 1;
    const int t = threadIdx.x;
#pragma unroll
    for (int i = 0; i < 4; i++) {
        int fi = t + i * 256;
        int kk = fi >> 4;
        int f  = fi & 15;
        float4 v = *(const float4*)&W1[(long)(bk * 64 + kk) * HID_DIM + bn * 64 + f * 4];
        T[kk][f * 4 + 0] = v.x; T[kk][f * 4 + 1] = v.y;
        T[kk][f * 4 + 2] = v.z; T[kk][f * 4 + 3] = v.w;
    }
    __syncthreads();
#pragma unroll
    for (int i = 0; i < 8; i++) {
        int di = t + i * 256;
        int n  = di >> 5;
        int dw = di & 31;
        unsigned lo = f2bf_rne(T[dw * 2 + 0][n]);
        unsigned hi = f2bf_rne(T[dw * 2 + 1][n]);
        unsigned short* dst = W1t + (long)(bn * 64 + n) * IN_DIM + bk * 64 + dw * 2;
        *(unsigned int*)dst = lo | (hi << 16);
    }
}

// ---------------------------------------------------------------------------
// wcvt2: W2t[64][128] bf16 = transpose(W2[128][64] fp32)   (one-shot, 1 blk)
// ---------------------------------------------------------------------------
__global__ __launch_bounds__(256) void wcvt2(const float* __restrict__ W2,
                                             unsigned short* __restrict__ W2t) {
    __shared__ float T[128][65];
    const int t = threadIdx.x;
#pragma unroll
    for (int i = 0; i < 8; i++) {
        int fi = t + i * 256;
        int k = fi >> 4;
        int f = fi & 15;
        float4 v = *(const float4*)&W2[(long)k * OUT_DIM + f * 4];
        T[k][f * 4 + 0] = v.x; T[k][f * 4 + 1] = v.y;
        T[k][f * 4 + 2] = v.z; T[k][f * 4 + 3] = v.w;
    }
    __syncthreads();
#pragma unroll
    for (int i = 0; i < 16; i++) {
        int di = t + i * 256;
        int n  = di >> 6;
        int dw = di & 63;
        unsigned lo = f2bf_rne(T[dw * 2 + 0][n]);
        unsigned hi = f2bf_rne(T[dw * 2 + 1][n]);
        *(unsigned int*)(W2t + (long)n * HID_DIM + dw * 2) = lo | (hi << 16);
    }
}

// ---------------------------------------------------------------------------
// gemm1_mfma: support_bf16[100000,128] = X[100000,512] @ W1  (bf16 MFMA)
// ---------------------------------------------------------------------------
__global__ __launch_bounds__(256) void gemm1_mfma(const float* __restrict__ X,
                                                  const unsigned short* __restrict__ W1t,
                                                  unsigned short* __restrict__ outb) {
    __shared__ unsigned short As[64][40];
    const int tid  = threadIdx.x;
    const int lane = tid & 63;
    const int w    = tid >> 6;
    const int m    = lane & 15;
    const int hi   = lane >> 4;
    const int rowBase = blockIdx.x * 64;

    f32x4 acc[4][2] = {};

    const int sr = tid >> 2;
    const int sk = (tid & 3) * 8;
    int gr = rowBase + sr;
    if (gr >= N_NODES) gr = N_NODES - 1;
    const float* xp = X + (long)gr * IN_DIM;

    const unsigned short* b0p = W1t + (long)(w * 32 + m) * IN_DIM + hi * 8;
    const unsigned short* b1p = W1t + (long)(w * 32 + 16 + m) * IN_DIM + hi * 8;

    for (int k0 = 0; k0 < IN_DIM; k0 += 32) {
        float4 xa = *(const float4*)(xp + k0 + sk);
        float4 xb = *(const float4*)(xp + k0 + sk + 4);
        uint4 pk;
        pk.x = f2bf_rne(xa.x) | (f2bf_rne(xa.y) << 16);
        pk.y = f2bf_rne(xa.z) | (f2bf_rne(xa.w) << 16);
        pk.z = f2bf_rne(xb.x) | (f2bf_rne(xb.y) << 16);
        pk.w = f2bf_rne(xb.z) | (f2bf_rne(xb.w) << 16);
        *(uint4*)&As[sr][sk] = pk;
        __syncthreads();

        bf16x8 bf0 = *(const bf16x8*)(b0p + k0);
        bf16x8 bf1 = *(const bf16x8*)(b1p + k0);
#pragma unroll
        for (int t = 0; t < 4; t++) {
            bf16x8 af = *(const bf16x8*)&As[t * 16 + m][hi * 8];
            acc[t][0] = __builtin_amdgcn_mfma_f32_16x16x32_bf16(af, bf0, acc[t][0], 0, 0, 0);
            acc[t][1] = __builtin_amdgcn_mfma_f32_16x16x32_bf16(af, bf1, acc[t][1], 0, 0, 0);
        }
        __syncthreads();
    }

    // D layout: col = lane&15, row = (lane>>4)*4 + reg ; store bf16
#pragma unroll
    for (int t = 0; t < 4; t++) {
#pragma unroll
        for (int r = 0; r < 4; r++) {
            int row = rowBase + t * 16 + hi * 4 + r;
            if (row < N_NODES) {
                outb[(long)row * HID_DIM + w * 32 + m] =
                    (unsigned short)f2bf_rne(acc[t][0][r]);
                outb[(long)row * HID_DIM + w * 32 + 16 + m] =
                    (unsigned short)f2bf_rne(acc[t][1][r]);
            }
        }
    }
}

// ---------------------------------------------------------------------------
// gemm2_mfma: hw[100000,64] fp32 = h_bf16[100000,128] @ W2  (W2 in registers)
// ---------------------------------------------------------------------------
__global__ __launch_bounds__(256) void gemm2_mfma(const unsigned short* __restrict__ hb,
                                                  const unsigned short* __restrict__ W2t,
                                                  float* __restrict__ hw) {
    const int tid  = threadIdx.x;
    const int lane = tid & 63;
    const int w    = tid >> 6;
    const int m    = lane & 15;
    const int hi   = lane >> 4;
    const long rowBase = (long)blockIdx.x * 128 + w * 32;

    bf16x8 bfrag[4][4];
#pragma unroll
    for (int nt = 0; nt < 4; nt++) {
        const unsigned short* bp = W2t + (long)(nt * 16 + m) * HID_DIM + hi * 8;
#pragma unroll
        for (int ks = 0; ks < 4; ks++)
            bfrag[ks][nt] = *(const bf16x8*)(bp + ks * 32);
    }

    f32x4 acc[2][4] = {};
#pragma unroll
    for (int mt = 0; mt < 2; mt++) {
        long r = rowBase + mt * 16 + m;
        if (r >= N_NODES) r = N_NODES - 1;
        const unsigned short* ap = hb + r * HID_DIM + hi * 8;
#pragma unroll
        for (int ks = 0; ks < 4; ks++) {
            bf16x8 af = *(const bf16x8*)(ap + ks * 32);
#pragma unroll
            for (int nt = 0; nt < 4; nt++)
                acc[mt][nt] = __builtin_amdgcn_mfma_f32_16x16x32_bf16(
                    af, bfrag[ks][nt], acc[mt][nt], 0, 0, 0);
        }
    }

#pragma unroll
    for (int mt = 0; mt < 2; mt++)
#pragma unroll
        for (int nt = 0; nt < 4; nt++)
#pragma unroll
            for (int r = 0; r < 4; r++) {
                long row = rowBase + mt * 16 + hi * 4 + r;
                if (row < N_NODES)
                    hw[row * OUT_DIM + nt * 16 + m] = acc[mt][nt][r];
            }
}

// ---------------------------------------------------------------------------
// CSR build: XCD-partitioned histogram -> scan -> XCD-partitioned scatter.
//
// Rows are split into 8 contiguous ranges; blockIdx.x & 7 selects the range,
// exploiting the (performance-only) round-robin blockIdx->XCD mapping so that
// each XCD's atomic counters and its contiguous ~1.6 MB sedge slice stay
// resident+dirty in that XCD's private L2 -> scattered 8B stores merge into
// full 64B lines (fixes the 112 MB WRITE_SIZE / 8x write amplification).
// Streaming edge reads are non-temporal so they don't evict the dirty region.
// Correctness does NOT depend on the XCD mapping (atomics give unique slots).
// ---------------------------------------------------------------------------
#define ROWS_PER_GRP (N_NODES / 8)   // 12500
#define CSR_BLOCKS 1024              // 8 groups x 128 blocks

__global__ __launch_bounds__(256) void hist_xcd(const int* __restrict__ rows,
                                                int* __restrict__ cnt) {
    const int grp = blockIdx.x & 7;
    const int rlo = grp * ROWS_PER_GRP;
    const int rhi = rlo + ROWS_PER_GRP;
    const int nb  = gridDim.x >> 3;
    const int bi  = blockIdx.x >> 3;
    for (int e = bi * 256 + threadIdx.x; e < N_EDGES; e += nb * 256) {
        int r = __builtin_nontemporal_load(&rows[e]);
        if (r >= rlo && r < rhi) atomicAdd(&cnt[r], 1);
    }
}

#define SCAN_BLOCKS ((N_NODES + 255) / 256)   // 391

__global__ __launch_bounds__(256) void scan_pass1(int* __restrict__ cnt,
                                                  int* __restrict__ bsum) {
    __shared__ int s[256];
    const int t = threadIdx.x;
    const int i = blockIdx.x * 256 + t;
    int v = (i < N_NODES) ? cnt[i] : 0;
    s[t] = v;
    __syncthreads();
    for (int off = 1; off < 256; off <<= 1) {
        int u = (t >= off) ? s[t - off] : 0;
        __syncthreads();
        s[t] += u;
        __syncthreads();
    }
    if (i < N_NODES) cnt[i] = s[t] - v;
    if (t == 255) bsum[blockIdx.x] = s[255];
}

__global__ __launch_bounds__(512) void scan_pass2(int* __restrict__ bsum,
                                                  int* __restrict__ boff) {
    __shared__ int s[512];
    const int t = threadIdx.x;
    int v = (t < SCAN_BLOCKS) ? bsum[t] : 0;
    s[t] = v;
    __syncthreads();
    for (int off = 1; off < 512; off <<= 1) {
        int u = (t >= off) ? s[t - off] : 0;
        __syncthreads();
        s[t] += u;
        __syncthreads();
    }
    if (t < SCAN_BLOCKS) boff[t] = s[t] - v;
}

__global__ __launch_bounds__(256) void scan_pass3(const int* __restrict__ cnt,
                                                  const int* __restrict__ boff,
                                                  int* __restrict__ rowptr,
                                                  int* __restrict__ cursor) {
    const int i = blockIdx.x * 256 + threadIdx.x;
    if (i < N_NODES) {
        int r = cnt[i] + boff[blockIdx.x];
        rowptr[i] = r;
        cursor[i] = r;
    }
    if (i == 0) rowptr[N_NODES] = N_EDGES;
}

__global__ __launch_bounds__(256) void scatter_xcd(const int* __restrict__ rows,
                                                   const int* __restrict__ cols,
                                                   const float* __restrict__ vals,
                                                   int* __restrict__ cursor,
                                                   int2* __restrict__ sedge) {
    const int grp = blockIdx.x & 7;
    const int rlo = grp * ROWS_PER_GRP;
    const int rhi = rlo + ROWS_PER_GRP;
    const int nb  = gridDim.x >> 3;
    const int bi  = blockIdx.x >> 3;
    for (int e = bi * 256 + threadIdx.x; e < N_EDGES; e += nb * 256) {
        int r = __builtin_nontemporal_load(&rows[e]);
        if (r >= rlo && r < rhi) {
            int   c = __builtin_nontemporal_load(&cols[e]);
            float v = __builtin_nontemporal_load(&vals[e]);
            int p = atomicAdd(&cursor[r], 1);
            sedge[p] = make_int2(c, __float_as_int(v));
        }
    }
}

// ---------------------------------------------------------------------------
// spmm1: h_bf16[row] = relu(sum v * support_bf16[col]) ; wave/row, D=128
// Lane-parallel edge fetch + readlane broadcast; 16 gathers in flight.
// ---------------------------------------------------------------------------
__global__ __launch_bounds__(256) void spmm1(const int* __restrict__ rowptr,
                                             const int2* __restrict__ sedge,
                                             const unsigned short* __restrict__ supb,
                                             unsigned short* __restrict__ outb) {
    const int wid = blockIdx.x * 4 + (threadIdx.x >> 6);
    if (wid >= N_NODES) return;
    const int lane = threadIdx.x & 63;
    const int start = rowptr[wid];
    const int end   = rowptr[wid + 1];

    float accx = 0.f, accy = 0.f;

    for (int base = start; base < end; base += 64) {
        int idx = base + lane;
        int ecol = 0, eval = 0;
        if (idx < end) {
            int2 e = sedge[idx];
            ecol = e.x; eval = e.y;
        }
        const int cnt = min(64, end - base);
        for (int k = 0; k < cnt; k += 16) {
            int   c[16];
            float v[16];
#pragma unroll
            for (int q = 0; q < 16; q++) {
                c[q] = __builtin_amdgcn_readlane(ecol, k + q);
                v[q] = __int_as_float(__builtin_amdgcn_readlane(eval, k + q));
            }
            unsigned u[16];
#pragma unroll
            for (int q = 0; q < 16; q++)
                u[q] = *(const unsigned*)(supb + (long)c[q] * 128 + lane * 2);
#pragma unroll
            for (int q = 0; q < 16; q++) {
                accx += v[q] * __uint_as_float(u[q] << 16);
                accy += v[q] * __uint_as_float(u[q] & 0xffff0000u);
            }
        }
    }

    accx = accx > 0.f ? accx : 0.f;
    accy = accy > 0.f ? accy : 0.f;
    *(unsigned int*)(outb + (long)wid * 128 + lane * 2) =
        f2bf_rne(accx) | (f2bf_rne(accy) << 16);
}

// ---------------------------------------------------------------------------
// spmm2: out[row] = sum v * hw[col] ; wave/row, D=64, fp32 (logits path)
// ---------------------------------------------------------------------------
__global__ __launch_bounds__(256) void spmm2(const int* __restrict__ rowptr,
                                             const int2* __restrict__ sedge,
                                             const float* __restrict__ dense,
                                             float* __restrict__ out) {
    const int wid = blockIdx.x * 4 + (threadIdx.x >> 6);
    if (wid >= N_NODES) return;
    const int lane = threadIdx.x & 63;
    const int start = rowptr[wid];
    const int end   = rowptr[wid + 1];

    float acc = 0.f;

    for (int base = start; base < end; base += 64) {
        int idx = base + lane;
        int ecol = 0, eval = 0;
        if (idx < end) {
            int2 e = sedge[idx];
            ecol = e.x; eval = e.y;
        }
        const int cnt = min(64, end - base);
        for (int k = 0; k < cnt; k += 16) {
            int   c[16];
            float v[16];
#pragma unroll
            for (int q = 0; q < 16; q++) {
                c[q] = __builtin_amdgcn_readlane(ecol, k + q);
                v[q] = __int_as_float(__builtin_amdgcn_readlane(eval, k + q));
            }
            float x[16];
#pragma unroll
            for (int q = 0; q < 16; q++)
                x[q] = dense[(long)c[q] * 64 + lane];
#pragma unroll
            for (int q = 0; q < 16; q++)
                acc += v[q] * x[q];
        }
    }

    out[(long)wid * 64 + lane] = acc;
}

// ---------------------------------------------------------------------------
extern "C" void kernel_launch(void* const* d_in, const int* in_sizes, int n_in,
                              void* d_out, int out_size, void* d_ws, size_t ws_size,
                              hipStream_t stream) {
    const float* feature = (const float*)d_in[0];
    const int*   erow    = (const int*)d_in[1];
    const int*   ecol    = (const int*)d_in[2];
    const float* evals   = (const float*)d_in[3];
    const float* W1      = (const float*)d_in[4];
    const float* W2      = (const float*)d_in[5];
    float* out = (float*)d_out;

    // workspace layout (~91 MB)
    unsigned short* supb = (unsigned short*)d_ws;                 // 25.6 MB bf16
    unsigned short* hb   = supb + (size_t)N_NODES * HID_DIM;      // 25.6 MB bf16
    float* hw      = (float*)(hb + (size_t)N_NODES * HID_DIM);    // 25.6 MB fp32
    int*   cnt     = (int*)(hw + (size_t)N_NODES * OUT_DIM);      // 400 KB
    int*   cursor  = cnt + N_NODES;                               // 400 KB
    int*   rowptr  = cursor + N_NODES;                            // 400 KB
    int2*  sedge   = (int2*)(rowptr + (N_NODES + 1));             // 12.8 MB
    int*   bsum    = (int*)(sedge + N_EDGES);                     // 1.6 KB
    int*   boff    = bsum + SCAN_BLOCKS;                          // 1.6 KB
    unsigned short* W1t = (unsigned short*)(boff + SCAN_BLOCKS);  // 128 KB bf16
    unsigned short* W2t = W1t + (size_t)HID_DIM * IN_DIM;         // 16 KB bf16

    // --- CSR build (counting sort by row, XCD-partitioned) ---
    hipMemsetAsync(cnt, 0, (size_t)N_NODES * sizeof(int), stream);
    hist_xcd<<<CSR_BLOCKS, 256, 0, stream>>>(erow, cnt);
    scan_pass1<<<SCAN_BLOCKS, 256, 0, stream>>>(cnt, bsum);
    scan_pass2<<<1, 512, 0, stream>>>(bsum, boff);
    scan_pass3<<<SCAN_BLOCKS, 256, 0, stream>>>(cnt, boff, rowptr, cursor);
    scatter_xcd<<<CSR_BLOCKS, 256, 0, stream>>>(erow, ecol, evals, cursor, sedge);

    // --- weight conversions (one-shot, tiny) ---
    wcvt<<<16, 256, 0, stream>>>(W1, W1t);
    wcvt2<<<1, 256, 0, stream>>>(W2, W2t);

    // layer 1: support = X @ W1  -> bf16
    gemm1_mfma<<<(N_NODES + 63) / 64, 256, 0, stream>>>(feature, W1t, supb);

    // h = relu(A @ support) -> bf16
    spmm1<<<(N_NODES + 3) / 4, 256, 0, stream>>>(rowptr, sedge, supb, hb);

    // hw = h @ W2 -> fp32
    gemm2_mfma<<<(N_NODES + 127) / 128, 256, 0, stream>>>(hb, W2t, hw);

    // logits = A @ hw
    spmm2<<<(N_NODES + 3) / 4, 256, 0, stream>>>(rowptr, sedge, hw, out);
}

// Round 4
// 602.619 us; speedup vs baseline: 1.0678x; 1.0060x over previous
//
#include <hip/hip_runtime.h>

#define N_NODES 100000
#define N_EDGES 1600000
#define IN_DIM 512
#define HID_DIM 128
#define OUT_DIM 64

typedef __attribute__((ext_vector_type(8))) short bf16x8;
typedef __attribute__((ext_vector_type(4))) float f32x4;

__device__ __forceinline__ unsigned int f2bf_rne(float f) {
    union { float f; unsigned u; } v; v.f = f;
    unsigned r = v.u + 0x7fffu + ((v.u >> 16) & 1u);   // round-to-nearest-even
    return r >> 16;
}

// ---------------------------------------------------------------------------
// wcvt: W1t[128][512] bf16 = transpose(W1[512][128] fp32)   (one-shot, 16 blk)
// ---------------------------------------------------------------------------
__global__ __launch_bounds__(256) void wcvt(const float* __restrict__ W1,
                                            unsigned short* __restrict__ W1t) {
    __shared__ float T[64][65];
    const int bk = blockIdx.x >> 1;
    const int bn = blockIdx.x & 1;
    const int t = threadIdx.x;
#pragma unroll
    for (int i = 0; i < 4; i++) {
        int fi = t + i * 256;
        int kk = fi >> 4;
        int f  = fi & 15;
        float4 v = *(const float4*)&W1[(long)(bk * 64 + kk) * HID_DIM + bn * 64 + f * 4];
        T[kk][f * 4 + 0] = v.x; T[kk][f * 4 + 1] = v.y;
        T[kk][f * 4 + 2] = v.z; T[kk][f * 4 + 3] = v.w;
    }
    __syncthreads();
#pragma unroll
    for (int i = 0; i < 8; i++) {
        int di = t + i * 256;
        int n  = di >> 5;
        int dw = di & 31;
        unsigned lo = f2bf_rne(T[dw * 2 + 0][n]);
        unsigned hi = f2bf_rne(T[dw * 2 + 1][n]);
        unsigned short* dst = W1t + (long)(bn * 64 + n) * IN_DIM + bk * 64 + dw * 2;
        *(unsigned int*)dst = lo | (hi << 16);
    }
}

// ---------------------------------------------------------------------------
// wcvt2: W2t[64][128] bf16 = transpose(W2[128][64] fp32)   (one-shot, 1 blk)
// ---------------------------------------------------------------------------
__global__ __launch_bounds__(256) void wcvt2(const float* __restrict__ W2,
                                             unsigned short* __restrict__ W2t) {
    __shared__ float T[128][65];
    const int t = threadIdx.x;
#pragma unroll
    for (int i = 0; i < 8; i++) {
        int fi = t + i * 256;
        int k = fi >> 4;
        int f = fi & 15;
        float4 v = *(const float4*)&W2[(long)k * OUT_DIM + f * 4];
        T[k][f * 4 + 0] = v.x; T[k][f * 4 + 1] = v.y;
        T[k][f * 4 + 2] = v.z; T[k][f * 4 + 3] = v.w;
    }
    __syncthreads();
#pragma unroll
    for (int i = 0; i < 16; i++) {
        int di = t + i * 256;
        int n  = di >> 6;
        int dw = di & 63;
        unsigned lo = f2bf_rne(T[dw * 2 + 0][n]);
        unsigned hi = f2bf_rne(T[dw * 2 + 1][n]);
        *(unsigned int*)(W2t + (long)n * HID_DIM + dw * 2) = lo | (hi << 16);
    }
}

// ---------------------------------------------------------------------------
// gemm1_mfma: support_bf16[100000,128] = X[100000,512] @ W1  (bf16 MFMA)
// ---------------------------------------------------------------------------
__global__ __launch_bounds__(256) void gemm1_mfma(const float* __restrict__ X,
                                                  const unsigned short* __restrict__ W1t,
                                                  unsigned short* __restrict__ outb) {
    __shared__ unsigned short As[64][40];
    const int tid  = threadIdx.x;
    const int lane = tid & 63;
    const int w    = tid >> 6;
    const int m    = lane & 15;
    const int hi   = lane >> 4;
    const int rowBase = blockIdx.x * 64;

    f32x4 acc[4][2] = {};

    const int sr = tid >> 2;
    const int sk = (tid & 3) * 8;
    int gr = rowBase + sr;
    if (gr >= N_NODES) gr = N_NODES - 1;
    const float* xp = X + (long)gr * IN_DIM;

    const unsigned short* b0p = W1t + (long)(w * 32 + m) * IN_DIM + hi * 8;
    const unsigned short* b1p = W1t + (long)(w * 32 + 16 + m) * IN_DIM + hi * 8;

    for (int k0 = 0; k0 < IN_DIM; k0 += 32) {
        float4 xa = *(const float4*)(xp + k0 + sk);
        float4 xb = *(const float4*)(xp + k0 + sk + 4);
        uint4 pk;
        pk.x = f2bf_rne(xa.x) | (f2bf_rne(xa.y) << 16);
        pk.y = f2bf_rne(xa.z) | (f2bf_rne(xa.w) << 16);
        pk.z = f2bf_rne(xb.x) | (f2bf_rne(xb.y) << 16);
        pk.w = f2bf_rne(xb.z) | (f2bf_rne(xb.w) << 16);
        *(uint4*)&As[sr][sk] = pk;
        __syncthreads();

        bf16x8 bf0 = *(const bf16x8*)(b0p + k0);
        bf16x8 bf1 = *(const bf16x8*)(b1p + k0);
#pragma unroll
        for (int t = 0; t < 4; t++) {
            bf16x8 af = *(const bf16x8*)&As[t * 16 + m][hi * 8];
            acc[t][0] = __builtin_amdgcn_mfma_f32_16x16x32_bf16(af, bf0, acc[t][0], 0, 0, 0);
            acc[t][1] = __builtin_amdgcn_mfma_f32_16x16x32_bf16(af, bf1, acc[t][1], 0, 0, 0);
        }
        __syncthreads();
    }

    // D layout: col = lane&15, row = (lane>>4)*4 + reg ; store bf16
#pragma unroll
    for (int t = 0; t < 4; t++) {
#pragma unroll
        for (int r = 0; r < 4; r++) {
            int row = rowBase + t * 16 + hi * 4 + r;
            if (row < N_NODES) {
                outb[(long)row * HID_DIM + w * 32 + m] =
                    (unsigned short)f2bf_rne(acc[t][0][r]);
                outb[(long)row * HID_DIM + w * 32 + 16 + m] =
                    (unsigned short)f2bf_rne(acc[t][1][r]);
            }
        }
    }
}

// ---------------------------------------------------------------------------
// gemm2_mfma: hwb[100000,64] BF16 = h_bf16[100000,128] @ W2  (W2 in registers)
// Output is bf16 now: halves the store traffic here and halves spmm2's
// gather traffic (row = 128 B instead of 256 B). Error contribution to the
// final logits is ~6e-3 (vs existing absmax 0.25 from upstream bf16 h).
// ---------------------------------------------------------------------------
__global__ __launch_bounds__(256) void gemm2_mfma(const unsigned short* __restrict__ hb,
                                                  const unsigned short* __restrict__ W2t,
                                                  unsigned short* __restrict__ hwb) {
    const int tid  = threadIdx.x;
    const int lane = tid & 63;
    const int w    = tid >> 6;
    const int m    = lane & 15;
    const int hi   = lane >> 4;
    const long rowBase = (long)blockIdx.x * 128 + w * 32;

    bf16x8 bfrag[4][4];
#pragma unroll
    for (int nt = 0; nt < 4; nt++) {
        const unsigned short* bp = W2t + (long)(nt * 16 + m) * HID_DIM + hi * 8;
#pragma unroll
        for (int ks = 0; ks < 4; ks++)
            bfrag[ks][nt] = *(const bf16x8*)(bp + ks * 32);
    }

    f32x4 acc[2][4] = {};
#pragma unroll
    for (int mt = 0; mt < 2; mt++) {
        long r = rowBase + mt * 16 + m;
        if (r >= N_NODES) r = N_NODES - 1;
        const unsigned short* ap = hb + r * HID_DIM + hi * 8;
#pragma unroll
        for (int ks = 0; ks < 4; ks++) {
            bf16x8 af = *(const bf16x8*)(ap + ks * 32);
#pragma unroll
            for (int nt = 0; nt < 4; nt++)
                acc[mt][nt] = __builtin_amdgcn_mfma_f32_16x16x32_bf16(
                    af, bfrag[ks][nt], acc[mt][nt], 0, 0, 0);
        }
    }

#pragma unroll
    for (int mt = 0; mt < 2; mt++)
#pragma unroll
        for (int nt = 0; nt < 4; nt++)
#pragma unroll
            for (int r = 0; r < 4; r++) {
                long row = rowBase + mt * 16 + hi * 4 + r;
                if (row < N_NODES)
                    hwb[row * OUT_DIM + nt * 16 + m] =
                        (unsigned short)f2bf_rne(acc[mt][nt][r]);
            }
}

// ---------------------------------------------------------------------------
// CSR build: XCD-partitioned histogram -> scan -> XCD-partitioned scatter.
// (validated round 3: scatter dropped out of the top-5 dispatches)
// ---------------------------------------------------------------------------
#define ROWS_PER_GRP (N_NODES / 8)   // 12500
#define CSR_BLOCKS 1024              // 8 groups x 128 blocks

__global__ __launch_bounds__(256) void hist_xcd(const int* __restrict__ rows,
                                                int* __restrict__ cnt) {
    const int grp = blockIdx.x & 7;
    const int rlo = grp * ROWS_PER_GRP;
    const int rhi = rlo + ROWS_PER_GRP;
    const int nb  = gridDim.x >> 3;
    const int bi  = blockIdx.x >> 3;
    for (int e = bi * 256 + threadIdx.x; e < N_EDGES; e += nb * 256) {
        int r = __builtin_nontemporal_load(&rows[e]);
        if (r >= rlo && r < rhi) atomicAdd(&cnt[r], 1);
    }
}

#define SCAN_BLOCKS ((N_NODES + 255) / 256)   // 391

__global__ __launch_bounds__(256) void scan_pass1(int* __restrict__ cnt,
                                                  int* __restrict__ bsum) {
    __shared__ int s[256];
    const int t = threadIdx.x;
    const int i = blockIdx.x * 256 + t;
    int v = (i < N_NODES) ? cnt[i] : 0;
    s[t] = v;
    __syncthreads();
    for (int off = 1; off < 256; off <<= 1) {
        int u = (t >= off) ? s[t - off] : 0;
        __syncthreads();
        s[t] += u;
        __syncthreads();
    }
    if (i < N_NODES) cnt[i] = s[t] - v;
    if (t == 255) bsum[blockIdx.x] = s[255];
}

__global__ __launch_bounds__(512) void scan_pass2(int* __restrict__ bsum,
                                                  int* __restrict__ boff) {
    __shared__ int s[512];
    const int t = threadIdx.x;
    int v = (t < SCAN_BLOCKS) ? bsum[t] : 0;
    s[t] = v;
    __syncthreads();
    for (int off = 1; off < 512; off <<= 1) {
        int u = (t >= off) ? s[t - off] : 0;
        __syncthreads();
        s[t] += u;
        __syncthreads();
    }
    if (t < SCAN_BLOCKS) boff[t] = s[t] - v;
}

__global__ __launch_bounds__(256) void scan_pass3(const int* __restrict__ cnt,
                                                  const int* __restrict__ boff,
                                                  int* __restrict__ rowptr,
                                                  int* __restrict__ cursor) {
    const int i = blockIdx.x * 256 + threadIdx.x;
    if (i < N_NODES) {
        int r = cnt[i] + boff[blockIdx.x];
        rowptr[i] = r;
        cursor[i] = r;
    }
    if (i == 0) rowptr[N_NODES] = N_EDGES;
}

__global__ __launch_bounds__(256) void scatter_xcd(const int* __restrict__ rows,
                                                   const int* __restrict__ cols,
                                                   const float* __restrict__ vals,
                                                   int* __restrict__ cursor,
                                                   int2* __restrict__ sedge) {
    const int grp = blockIdx.x & 7;
    const int rlo = grp * ROWS_PER_GRP;
    const int rhi = rlo + ROWS_PER_GRP;
    const int nb  = gridDim.x >> 3;
    const int bi  = blockIdx.x >> 3;
    for (int e = bi * 256 + threadIdx.x; e < N_EDGES; e += nb * 256) {
        int r = __builtin_nontemporal_load(&rows[e]);
        if (r >= rlo && r < rhi) {
            int   c = __builtin_nontemporal_load(&cols[e]);
            float v = __builtin_nontemporal_load(&vals[e]);
            int p = atomicAdd(&cursor[r], 1);
            sedge[p] = make_int2(c, __float_as_int(v));
        }
    }
}

// ---------------------------------------------------------------------------
// spmm1: h_bf16[row] = relu(sum v * support_bf16[col]) ; wave/row, D=128
// Lane-parallel edge fetch + readlane broadcast; 16 gathers in flight.
// ---------------------------------------------------------------------------
__global__ __launch_bounds__(256) void spmm1(const int* __restrict__ rowptr,
                                             const int2* __restrict__ sedge,
                                             const unsigned short* __restrict__ supb,
                                             unsigned short* __restrict__ outb) {
    const int wid = blockIdx.x * 4 + (threadIdx.x >> 6);
    if (wid >= N_NODES) return;
    const int lane = threadIdx.x & 63;
    const int start = rowptr[wid];
    const int end   = rowptr[wid + 1];

    float accx = 0.f, accy = 0.f;

    for (int base = start; base < end; base += 64) {
        int idx = base + lane;
        int ecol = 0, eval = 0;
        if (idx < end) {
            int2 e = sedge[idx];
            ecol = e.x; eval = e.y;
        }
        const int cnt = min(64, end - base);
        for (int k = 0; k < cnt; k += 16) {
            int   c[16];
            float v[16];
#pragma unroll
            for (int q = 0; q < 16; q++) {
                c[q] = __builtin_amdgcn_readlane(ecol, k + q);
                v[q] = __int_as_float(__builtin_amdgcn_readlane(eval, k + q));
            }
            unsigned u[16];
#pragma unroll
            for (int q = 0; q < 16; q++)
                u[q] = *(const unsigned*)(supb + (long)c[q] * 128 + lane * 2);
#pragma unroll
            for (int q = 0; q < 16; q++) {
                accx += v[q] * __uint_as_float(u[q] << 16);
                accy += v[q] * __uint_as_float(u[q] & 0xffff0000u);
            }
        }
    }

    accx = accx > 0.f ? accx : 0.f;
    accy = accy > 0.f ? accy : 0.f;
    *(unsigned int*)(outb + (long)wid * 128 + lane * 2) =
        f2bf_rne(accx) | (f2bf_rne(accy) << 16);
}

// ---------------------------------------------------------------------------
// spmm2: out[row] = sum v * hwb[col] ; wave/row, D=64, bf16 gather operand.
// Row = 64 bf16 = 128 B -> 2 edges per wave: lanes 0-31 take even edges,
// lanes 32-63 take odd edges; each lane gathers one dword (2 bf16 dims).
// Cross-half reduce via shfl_xor(32); half-wave float2 stores.
// Padding lanes carry {col=0,val=0} so no tail handling is needed.
// ---------------------------------------------------------------------------
__global__ __launch_bounds__(256) void spmm2(const int* __restrict__ rowptr,
                                             const int2* __restrict__ sedge,
                                             const unsigned short* __restrict__ hwb,
                                             float* __restrict__ out) {
    const int wid = blockIdx.x * 4 + (threadIdx.x >> 6);
    if (wid >= N_NODES) return;
    const int lane = threadIdx.x & 63;
    const int half = lane >> 5;
    const int hl   = lane & 31;
    const int start = rowptr[wid];
    const int end   = rowptr[wid + 1];

    float accx = 0.f, accy = 0.f;

    for (int base = start; base < end; base += 64) {
        int idx = base + lane;
        int ecol = 0, eval = 0;
        if (idx < end) {
            int2 e = sedge[idx];
            ecol = e.x; eval = e.y;
        }
        const int cnt = min(64, end - base);
        for (int k = 0; k < cnt; k += 16) {   // 16 edges = 8 pair-steps
            int   c[8];
            float v[8];
#pragma unroll
            for (int q = 0; q < 8; q++) {
                int c0 = __builtin_amdgcn_readlane(ecol, k + 2 * q);
                int c1 = __builtin_amdgcn_readlane(ecol, k + 2 * q + 1);
                int v0 = __builtin_amdgcn_readlane(eval, k + 2 * q);
                int v1 = __builtin_amdgcn_readlane(eval, k + 2 * q + 1);
                c[q] = half ? c1 : c0;
                v[q] = __int_as_float(half ? v1 : v0);
            }
            unsigned u[8];
#pragma unroll
            for (int q = 0; q < 8; q++)
                u[q] = *(const unsigned*)(hwb + (long)c[q] * OUT_DIM + hl * 2);
#pragma unroll
            for (int q = 0; q < 8; q++) {
                accx += v[q] * __uint_as_float(u[q] << 16);
                accy += v[q] * __uint_as_float(u[q] & 0xffff0000u);
            }
        }
    }

    accx += __shfl_xor(accx, 32);
    accy += __shfl_xor(accy, 32);
    if (half == 0) {
        float2 o = make_float2(accx, accy);
        *(float2*)(out + (long)wid * OUT_DIM + hl * 2) = o;
    }
}

// ---------------------------------------------------------------------------
extern "C" void kernel_launch(void* const* d_in, const int* in_sizes, int n_in,
                              void* d_out, int out_size, void* d_ws, size_t ws_size,
                              hipStream_t stream) {
    const float* feature = (const float*)d_in[0];
    const int*   erow    = (const int*)d_in[1];
    const int*   ecol    = (const int*)d_in[2];
    const float* evals   = (const float*)d_in[3];
    const float* W1      = (const float*)d_in[4];
    const float* W2      = (const float*)d_in[5];
    float* out = (float*)d_out;

    // workspace layout (~78 MB)
    unsigned short* supb = (unsigned short*)d_ws;                 // 25.6 MB bf16
    unsigned short* hb   = supb + (size_t)N_NODES * HID_DIM;      // 25.6 MB bf16
    unsigned short* hwb  = hb + (size_t)N_NODES * HID_DIM;        // 12.8 MB bf16
    int*   cnt     = (int*)(hwb + (size_t)N_NODES * OUT_DIM);     // 400 KB
    int*   cursor  = cnt + N_NODES;                               // 400 KB
    int*   rowptr  = cursor + N_NODES;                            // 400 KB (+pad)
    int2*  sedge   = (int2*)(rowptr + (N_NODES + 2));             // 12.8 MB (8B-aligned)
    int*   bsum    = (int*)(sedge + N_EDGES);                     // 1.6 KB
    int*   boff    = bsum + SCAN_BLOCKS;                          // 1.6 KB
    unsigned short* W1t = (unsigned short*)(boff + SCAN_BLOCKS);  // 128 KB bf16
    unsigned short* W2t = W1t + (size_t)HID_DIM * IN_DIM;         // 16 KB bf16

    // --- CSR build (counting sort by row, XCD-partitioned) ---
    hipMemsetAsync(cnt, 0, (size_t)N_NODES * sizeof(int), stream);
    hist_xcd<<<CSR_BLOCKS, 256, 0, stream>>>(erow, cnt);
    scan_pass1<<<SCAN_BLOCKS, 256, 0, stream>>>(cnt, bsum);
    scan_pass2<<<1, 512, 0, stream>>>(bsum, boff);
    scan_pass3<<<SCAN_BLOCKS, 256, 0, stream>>>(cnt, boff, rowptr, cursor);
    scatter_xcd<<<CSR_BLOCKS, 256, 0, stream>>>(erow, ecol, evals, cursor, sedge);

    // --- weight conversions (one-shot, tiny) ---
    wcvt<<<16, 256, 0, stream>>>(W1, W1t);
    wcvt2<<<1, 256, 0, stream>>>(W2, W2t);

    // layer 1: support = X @ W1  -> bf16
    gemm1_mfma<<<(N_NODES + 63) / 64, 256, 0, stream>>>(feature, W1t, supb);

    // h = relu(A @ support) -> bf16
    spmm1<<<(N_NODES + 3) / 4, 256, 0, stream>>>(rowptr, sedge, supb, hb);

    // hwb = h @ W2 -> bf16
    gemm2_mfma<<<(N_NODES + 127) / 128, 256, 0, stream>>>(hb, W2t, hwb);

    // logits = A @ hwb
    spmm2<<<(N_NODES + 3) / 4, 256, 0, stream>>>(rowptr, sedge, hwb, out);
}